// Round 9
// baseline (76.126 us; speedup 1.0000x reference)
//
#include <hip/hip_runtime.h>

// out = f1>=0 ? f1*winMax9x9(f2pad) : f1*winMin9x9(f2pad)  (separable 9-window)
// R5 structure (best: 43.5us): vertical-first van Herk from global (coalesced,
// lane=column), bank-uniform LDS planes, ONE lgkm-only barrier, horizontal
// van Herk + sign-select multiply. R9 change: NONTEMPORAL stores for out --
// out is never re-read; keeping it out of LLC preserves f1/f2 residency
// across graph replays (254 MB working set vs 256 MB LLC was thrashing).

#define HH 38
#define WW 68
#define PLANE (HH * WW)    // 2584
#define HMS 81             // LDS row stride (floats): 4 left pad | 68 data | 9 right pad
#define TPB 320
#define NB (16 * 512)

#define BAR() do { asm volatile("s_waitcnt lgkmcnt(0)" ::: "memory"); \
                   __builtin_amdgcn_s_barrier();                      \
                   __builtin_amdgcn_sched_barrier(0); } while (0)

__global__ __launch_bounds__(TPB) void corr_vh_nt_kernel(
    const float* __restrict__ f1, const float* __restrict__ f2,
    float* __restrict__ out)
{
    __shared__ float hmx[HH * HMS];   // vertical 9-window max, padded cols
    __shared__ float hmn[HH * HMS];   // vertical 9-window min

    const int t = threadIdx.x;
    const int base = blockIdx.x * PLANE;
    const float* __restrict__ f2p = f2 + base;

    // ---- zero pad columns (phys 0..3 and 72..79) of both planes ----
    for (int i = t; i < 456; i += TPB) {          // 38 rows x 12 pad cols
        int r = i / 12, j = i % 12;
        int c = (j < 4) ? j : j + 68;
        hmx[r * HMS + c] = 0.0f;
        hmn[r * HMS + c] = 0.0f;
    }

    // ---- prefetch f1 for the horizontal phase (in flight across the barrier) ----
    const int hr = t >> 3, hseg = t & 7, hc0 = hseg * 9;
    float fr[9];
    if (t < 304) {
        #pragma unroll
        for (int k = 0; k < 9; ++k)
            fr[k] = (hc0 + k < WW) ? f1[base + hr * WW + hc0 + k] : 0.0f;
    }

    // ---- vertical 9-window MAX+MIN via van Herk, global -> LDS ----
    if (t < 272) {                                // 68 cols x 4 segments of 10 rows
        const int col = t % WW, seg = t / WW;
        const int h0 = (seg == 3) ? 28 : seg * 10;   // overlap trick, no row predicate
        float v[18];
        #pragma unroll
        for (int i = 0; i < 18; ++i) {
            int row = h0 - 4 + i;
            v[i] = (row >= 0 && row < HH) ? f2p[row * WW + col] : 0.0f;
        }
        float S[9], P[9];
        // max: suffix over v[0..8], prefix over v[9..17]; window k = v[k..k+8]
        S[8] = v[8];
        #pragma unroll
        for (int i = 7; i >= 0; --i) S[i] = fmaxf(v[i], S[i + 1]);
        P[0] = v[9];
        #pragma unroll
        for (int i = 1; i < 9; ++i) P[i] = fmaxf(P[i - 1], v[9 + i]);
        hmx[(h0 + 0) * HMS + 4 + col] = S[0];
        #pragma unroll
        for (int k = 1; k < 9; ++k)
            hmx[(h0 + k) * HMS + 4 + col] = fmaxf(S[k], P[k - 1]);
        hmx[(h0 + 9) * HMS + 4 + col] = P[8];
        // min
        S[8] = v[8];
        #pragma unroll
        for (int i = 7; i >= 0; --i) S[i] = fminf(v[i], S[i + 1]);
        P[0] = v[9];
        #pragma unroll
        for (int i = 1; i < 9; ++i) P[i] = fminf(P[i - 1], v[9 + i]);
        hmn[(h0 + 0) * HMS + 4 + col] = S[0];
        #pragma unroll
        for (int k = 1; k < 9; ++k)
            hmn[(h0 + k) * HMS + 4 + col] = fminf(S[k], P[k - 1]);
        hmn[(h0 + 9) * HMS + 4 + col] = P[8];
    }

    BAR();   // LDS ready; f1 prefetch loads keep flying (no vmcnt drain)

    // ---- horizontal 9-window MAX+MIN via van Herk + combine + NT store ----
    if (t < 304) {                                // 38 rows x 8 segments of 9 cols
        float u[17];
        float S[9], P[9], wx[9];
        // max from hmx: u[i] = phys col hc0+i = real col hc0-4+i
        #pragma unroll
        for (int i = 0; i < 17; ++i) u[i] = hmx[hr * HMS + hc0 + i];
        S[8] = u[8];
        #pragma unroll
        for (int i = 7; i >= 0; --i) S[i] = fmaxf(u[i], S[i + 1]);
        P[0] = u[9];
        #pragma unroll
        for (int i = 1; i < 9; ++i) P[i] = fmaxf(P[i - 1], u[9 + i]);
        wx[0] = S[0];
        #pragma unroll
        for (int k = 1; k < 9; ++k) wx[k] = fmaxf(S[k], P[k - 1]);
        // min from hmn
        #pragma unroll
        for (int i = 0; i < 17; ++i) u[i] = hmn[hr * HMS + hc0 + i];
        S[8] = u[8];
        #pragma unroll
        for (int i = 7; i >= 0; --i) S[i] = fminf(u[i], S[i + 1]);
        P[0] = u[9];
        #pragma unroll
        for (int i = 1; i < 9; ++i) P[i] = fminf(P[i - 1], u[9 + i]);
        #pragma unroll
        for (int k = 0; k < 9; ++k) {
            int c = hc0 + k;
            if (c < WW) {
                float wn = (k == 0) ? S[0] : fminf(S[k], P[k - 1]);
                float a = fr[k];
                float res = a * (a >= 0.0f ? wx[k] : wn);
                __builtin_nontemporal_store(res, &out[base + hr * WW + c]);
            }
        }
    }
}

extern "C" void kernel_launch(void* const* d_in, const int* in_sizes, int n_in,
                              void* d_out, int out_size, void* d_ws, size_t ws_size,
                              hipStream_t stream) {
    const float* f1 = (const float*)d_in[0];
    const float* f2 = (const float*)d_in[1];
    float* out = (float*)d_out;
    corr_vh_nt_kernel<<<dim3(NB), dim3(TPB), 0, stream>>>(f1, f2, out);
}

// Round 10
// 43.511 us; speedup vs baseline: 1.7496x; 1.7496x over previous
//
#include <hip/hip_runtime.h>

// out = f1>=0 ? f1*winMax9x9(f2pad) : f1*winMin9x9(f2pad)  (separable 9-window)
// R5 structure (best: 43.5us): vertical-first van Herk from global (coalesced,
// lane=column), ONE lgkm-only barrier, horizontal van Herk + sign-select mult.
// R10 change: HMS 81 -> 84. Phase-H bank index = (HMS%32)*r + 9*s + i;
// 84%32=20 makes the 64-lane map exactly 2-to-1 per bank (free on CDNA4),
// vs 81%32=17 which gave 4-way hits (3.2M conflict cycles ~= 12% of runtime).

#define HH 38
#define WW 68
#define PLANE (HH * WW)    // 2584
#define HMS 84             // LDS row stride (floats): 4 pad | 68 data | 12 pad/slack
#define TPB 320
#define NB (16 * 512)

#define BAR() do { asm volatile("s_waitcnt lgkmcnt(0)" ::: "memory"); \
                   __builtin_amdgcn_s_barrier();                      \
                   __builtin_amdgcn_sched_barrier(0); } while (0)

__global__ __launch_bounds__(TPB) void corr_vh84_kernel(
    const float* __restrict__ f1, const float* __restrict__ f2,
    float* __restrict__ out)
{
    __shared__ float hmx[HH * HMS];   // vertical 9-window max, padded cols
    __shared__ float hmn[HH * HMS];   // vertical 9-window min

    const int t = threadIdx.x;
    const int base = blockIdx.x * PLANE;
    const float* __restrict__ f2p = f2 + base;

    // ---- zero pad columns (phys 0..3 and 72..79) of both planes ----
    for (int i = t; i < 456; i += TPB) {          // 38 rows x 12 pad cols
        int r = i / 12, j = i % 12;
        int c = (j < 4) ? j : j + 68;
        hmx[r * HMS + c] = 0.0f;
        hmn[r * HMS + c] = 0.0f;
    }

    // ---- prefetch f1 for the horizontal phase (in flight across the barrier) ----
    const int hr = t >> 3, hseg = t & 7, hc0 = hseg * 9;
    float fr[9];
    if (t < 304) {
        #pragma unroll
        for (int k = 0; k < 9; ++k)
            fr[k] = (hc0 + k < WW) ? f1[base + hr * WW + hc0 + k] : 0.0f;
    }

    // ---- vertical 9-window MAX+MIN via van Herk, global -> LDS ----
    if (t < 272) {                                // 68 cols x 4 segments of 10 rows
        const int col = t % WW, seg = t / WW;
        const int h0 = (seg == 3) ? 28 : seg * 10;   // overlap trick, no row predicate
        float v[18];
        #pragma unroll
        for (int i = 0; i < 18; ++i) {
            int row = h0 - 4 + i;
            v[i] = (row >= 0 && row < HH) ? f2p[row * WW + col] : 0.0f;
        }
        float S[9], P[9];
        // max: suffix over v[0..8], prefix over v[9..17]; window k = v[k..k+8]
        S[8] = v[8];
        #pragma unroll
        for (int i = 7; i >= 0; --i) S[i] = fmaxf(v[i], S[i + 1]);
        P[0] = v[9];
        #pragma unroll
        for (int i = 1; i < 9; ++i) P[i] = fmaxf(P[i - 1], v[9 + i]);
        hmx[(h0 + 0) * HMS + 4 + col] = S[0];
        #pragma unroll
        for (int k = 1; k < 9; ++k)
            hmx[(h0 + k) * HMS + 4 + col] = fmaxf(S[k], P[k - 1]);
        hmx[(h0 + 9) * HMS + 4 + col] = P[8];
        // min
        S[8] = v[8];
        #pragma unroll
        for (int i = 7; i >= 0; --i) S[i] = fminf(v[i], S[i + 1]);
        P[0] = v[9];
        #pragma unroll
        for (int i = 1; i < 9; ++i) P[i] = fminf(P[i - 1], v[9 + i]);
        hmn[(h0 + 0) * HMS + 4 + col] = S[0];
        #pragma unroll
        for (int k = 1; k < 9; ++k)
            hmn[(h0 + k) * HMS + 4 + col] = fminf(S[k], P[k - 1]);
        hmn[(h0 + 9) * HMS + 4 + col] = P[8];
    }

    BAR();   // LDS ready; f1 prefetch loads keep flying (no vmcnt drain)

    // ---- horizontal 9-window MAX+MIN via van Herk + combine + store ----
    if (t < 304) {                                // 38 rows x 8 segments of 9 cols
        float u[17];
        float S[9], P[9], wx[9];
        // max from hmx: u[i] = phys col hc0+i = real col hc0-4+i
        #pragma unroll
        for (int i = 0; i < 17; ++i) u[i] = hmx[hr * HMS + hc0 + i];
        S[8] = u[8];
        #pragma unroll
        for (int i = 7; i >= 0; --i) S[i] = fmaxf(u[i], S[i + 1]);
        P[0] = u[9];
        #pragma unroll
        for (int i = 1; i < 9; ++i) P[i] = fmaxf(P[i - 1], u[9 + i]);
        wx[0] = S[0];
        #pragma unroll
        for (int k = 1; k < 9; ++k) wx[k] = fmaxf(S[k], P[k - 1]);
        // min from hmn
        #pragma unroll
        for (int i = 0; i < 17; ++i) u[i] = hmn[hr * HMS + hc0 + i];
        S[8] = u[8];
        #pragma unroll
        for (int i = 7; i >= 0; --i) S[i] = fminf(u[i], S[i + 1]);
        P[0] = u[9];
        #pragma unroll
        for (int i = 1; i < 9; ++i) P[i] = fminf(P[i - 1], u[9 + i]);
        #pragma unroll
        for (int k = 0; k < 9; ++k) {
            int c = hc0 + k;
            if (c < WW) {
                float wn = (k == 0) ? S[0] : fminf(S[k], P[k - 1]);
                float a = fr[k];
                out[base + hr * WW + c] = a * (a >= 0.0f ? wx[k] : wn);
            }
        }
    }
}

extern "C" void kernel_launch(void* const* d_in, const int* in_sizes, int n_in,
                              void* d_out, int out_size, void* d_ws, size_t ws_size,
                              hipStream_t stream) {
    const float* f1 = (const float*)d_in[0];
    const float* f2 = (const float*)d_in[1];
    float* out = (float*)d_out;
    corr_vh84_kernel<<<dim3(NB), dim3(TPB), 0, stream>>>(f1, f2, out);
}